// Round 1
// baseline (1832.495 us; speedup 1.0000x reference)
//
#include <hip/hip_runtime.h>
#include <stdint.h>

#define TOK 2048
#define HID 4096
#define VOC 32000

typedef __attribute__((ext_vector_type(4))) float f32x4;
typedef __attribute__((ext_vector_type(8))) short bf16x8;
typedef __attribute__((ext_vector_type(8))) unsigned short u16x8;

__device__ __forceinline__ float bf2f(unsigned short u) {
  return __uint_as_float(((unsigned int)u) << 16);
}
__device__ __forceinline__ unsigned short f2bf(float f) {
  unsigned int u = __float_as_uint(f);
  u += 0x7FFFu + ((u >> 16) & 1u);  // round-to-nearest-even
  return (unsigned short)(u >> 16);
}

// ---------------- cast f32 -> bf16 ----------------
__global__ __launch_bounds__(256) void cast_f32_bf16(const float* __restrict__ in,
                                                     unsigned short* __restrict__ out,
                                                     long n) {
  long i = ((long)blockIdx.x * 256 + threadIdx.x) * 4;
  const long stride = (long)gridDim.x * 256 * 4;
  for (; i < n; i += stride) {
    const float4 v = *(const float4*)(in + i);
    ushort4 o;
    o.x = f2bf(v.x); o.y = f2bf(v.y); o.z = f2bf(v.z); o.w = f2bf(v.w);
    *(ushort4*)(out + i) = o;
  }
}

// ---------------- async global -> LDS (16B/lane) ----------------
__device__ __forceinline__ void gload_lds16(const void* g, void* l) {
  __builtin_amdgcn_global_load_lds(
      (const __attribute__((address_space(1))) unsigned int*)(uintptr_t)g,
      (__attribute__((address_space(3))) unsigned int*)(uintptr_t)l,
      16, 0, 0);
}

// ---------------- bf16 GEMM: C[M,N] = A[M,K] * B[N,K]^T, bf16 out ----------------
// m97 structure: 128x128 tile, BK=64, 4 waves (2x2 of 64x64), global_load_lds w16,
// 2-barrier K-loop, mfma_f32_16x16x32_bf16.
__global__ __launch_bounds__(256) void gemm_bt(const unsigned short* __restrict__ A,
                                               const unsigned short* __restrict__ B,
                                               unsigned short* __restrict__ C) {
  __shared__ unsigned short As[128 * 64];
  __shared__ unsigned short Bs[128 * 64];
  const int tid = threadIdx.x;
  const int w = tid >> 6;
  const int l = tid & 63;
  const int mt = blockIdx.x;   // token tile (fast dim -> 16 blocks share a W tile)
  const int nt = blockIdx.y;   // vocab tile
  const int wm = (w >> 1) * 64;
  const int wn = (w & 1) * 64;

  f32x4 acc[4][4] = {};

  // staging source: chunk c covers LDS bytes [c*1024,(c+1)*1024) = rows c*8..c*8+7
  // lane l -> row c*8 + (l>>3), element col (l&7)*8  (HW writes lds base + l*16)
  const int srow = l >> 3;
  const int scol = (l & 7) * 8;
  const size_t abase = ((size_t)mt * 128 + srow) * HID + scol;
  const size_t bbase = ((size_t)nt * 128 + srow) * HID + scol;

  for (int kt = 0; kt < HID; kt += 64) {
#pragma unroll
    for (int i = 0; i < 4; ++i) {
      const int c = w * 4 + i;
      gload_lds16(A + abase + (size_t)(c * 8) * HID + kt, &As[c * 512]);
      gload_lds16(B + bbase + (size_t)(c * 8) * HID + kt, &Bs[c * 512]);
    }
    __syncthreads();  // compiler drains vmcnt before barrier -> LDS ready
    const int lr = l & 15;
#pragma unroll
    for (int kk = 0; kk < 64; kk += 32) {
      const int lk = kk + (l >> 4) * 8;
      bf16x8 af[4], bfr[4];
#pragma unroll
      for (int mf = 0; mf < 4; ++mf)
        af[mf] = *(const bf16x8*)&As[(wm + mf * 16 + lr) * 64 + lk];
#pragma unroll
      for (int nf = 0; nf < 4; ++nf)
        bfr[nf] = *(const bf16x8*)&Bs[(wn + nf * 16 + lr) * 64 + lk];
#pragma unroll
      for (int mf = 0; mf < 4; ++mf)
#pragma unroll
        for (int nf = 0; nf < 4; ++nf)
          acc[mf][nf] = __builtin_amdgcn_mfma_f32_16x16x32_bf16(af[mf], bfr[nf],
                                                                acc[mf][nf], 0, 0, 0);
    }
    __syncthreads();
  }

  // epilogue: D col = lane&15 (N), row = (lane>>4)*4 + reg (M)  [m89-verified]
  const int lr = l & 15;
  const int lg = (l >> 4) * 4;
#pragma unroll
  for (int mf = 0; mf < 4; ++mf)
#pragma unroll
    for (int nf = 0; nf < 4; ++nf)
#pragma unroll
      for (int r = 0; r < 4; ++r) {
        const int row = mt * 128 + wm + mf * 16 + lg + r;
        const int col = nt * 128 + wn + nf * 16 + lr;
        C[(size_t)row * VOC + col] = f2bf(acc[mf][nf][r]);
      }
}

// ---------------- per-token JSD ----------------
__device__ __forceinline__ void merge_ms(float& m, float& s, float om, float os) {
  float nm = fmaxf(m, om);
  s = s * __expf(m - nm) + os * __expf(om - nm);
  m = nm;
}

__global__ __launch_bounds__(256) void jsd_kernel(const unsigned short* __restrict__ SL,
                                                  const unsigned short* __restrict__ TL,
                                                  float* __restrict__ partials) {
  const int t = blockIdx.x;
  const int tid = threadIdx.x;
  const unsigned short* srow = SL + (size_t)t * VOC;
  const unsigned short* trow = TL + (size_t)t * VOC;

  // pass 1: online logsumexp for student (s) and teacher (t)
  float ms = -INFINITY, ss = 0.f, mt_ = -INFINITY, st = 0.f;
  for (int c = tid; c < VOC / 8; c += 256) {
    u16x8 vs = *(const u16x8*)(srow + c * 8);
    u16x8 vt = *(const u16x8*)(trow + c * 8);
    float zs[8], zt[8];
    float m8s = -INFINITY, m8t = -INFINITY;
#pragma unroll
    for (int j = 0; j < 8; ++j) {
      zs[j] = bf2f(vs[j]); zt[j] = bf2f(vt[j]);
      m8s = fmaxf(m8s, zs[j]); m8t = fmaxf(m8t, zt[j]);
    }
    float nms = fmaxf(ms, m8s);
    float es = 0.f;
#pragma unroll
    for (int j = 0; j < 8; ++j) es += __expf(zs[j] - nms);
    ss = ss * __expf(ms - nms) + es; ms = nms;
    float nmt = fmaxf(mt_, m8t);
    float et = 0.f;
#pragma unroll
    for (int j = 0; j < 8; ++j) et += __expf(zt[j] - nmt);
    st = st * __expf(mt_ - nmt) + et; mt_ = nmt;
  }
#pragma unroll
  for (int off = 32; off > 0; off >>= 1) {
    float om = __shfl_xor(ms, off), os = __shfl_xor(ss, off);
    merge_ms(ms, ss, om, os);
    float omt = __shfl_xor(mt_, off), ost = __shfl_xor(st, off);
    merge_ms(mt_, st, omt, ost);
  }
  __shared__ float red[4][4];
  const int w = tid >> 6;
  if ((tid & 63) == 0) { red[w][0] = ms; red[w][1] = ss; red[w][2] = mt_; red[w][3] = st; }
  __syncthreads();
  float Ms = red[0][0], Ss = red[0][1], Mt = red[0][2], St = red[0][3];
#pragma unroll
  for (int i = 1; i < 4; ++i) {
    merge_ms(Ms, Ss, red[i][0], red[i][1]);
    merge_ms(Mt, St, red[i][2], red[i][3]);
  }
  const float logZs = Ms + __logf(Ss);
  const float logZt = Mt + __logf(St);

  // pass 2: jsd = 0.5*p*(lp-lm) + 0.5*q*(lq-lm),  lm = log(0.5) + logaddexp(lp,lq)
  float acc = 0.f;
  for (int c = tid; c < VOC / 8; c += 256) {
    u16x8 vs = *(const u16x8*)(srow + c * 8);
    u16x8 vt = *(const u16x8*)(trow + c * 8);
#pragma unroll
    for (int j = 0; j < 8; ++j) {
      float lq = bf2f(vs[j]) - logZs;
      float lp = bf2f(vt[j]) - logZt;
      float mx = fmaxf(lp, lq), mn = fminf(lp, lq);
      float lm = mx + log1pf(__expf(mn - mx)) - 0.69314718f;
      acc += __expf(lp) * (lp - lm) + __expf(lq) * (lq - lm);
    }
  }
  acc *= 0.5f;
#pragma unroll
  for (int off = 32; off > 0; off >>= 1) acc += __shfl_xor(acc, off);
  __shared__ float red2[4];
  if ((tid & 63) == 0) red2[w] = acc;
  __syncthreads();
  if (tid == 0) partials[t] = red2[0] + red2[1] + red2[2] + red2[3];
}

__global__ __launch_bounds__(256) void final_reduce(const float* __restrict__ partials,
                                                    float* __restrict__ out) {
  float a = 0.f;
  for (int i = threadIdx.x; i < TOK; i += 256) a += partials[i];
#pragma unroll
  for (int off = 32; off > 0; off >>= 1) a += __shfl_xor(a, off);
  __shared__ float red[4];
  const int w = threadIdx.x >> 6;
  if ((threadIdx.x & 63) == 0) red[w] = a;
  __syncthreads();
  if (threadIdx.x == 0) out[0] = (red[0] + red[1] + red[2] + red[3]) * (1.0f / TOK);
}

// ---------------- launch ----------------
extern "C" void kernel_launch(void* const* d_in, const int* in_sizes, int n_in,
                              void* d_out, int out_size, void* d_ws, size_t ws_size,
                              hipStream_t stream) {
  const float* sIn = (const float*)d_in[0];
  const float* tIn = (const float*)d_in[1];
  const float* sW  = (const float*)d_in[2];
  const float* tW  = (const float*)d_in[3];
  float* out = (float*)d_out;

  unsigned short* ws = (unsigned short*)d_ws;
  unsigned short* sA  = ws;                        // 2048*4096 bf16
  unsigned short* tA  = sA  + (long)TOK * HID;     // 2048*4096
  unsigned short* sWb = tA  + (long)TOK * HID;     // 32000*4096
  unsigned short* tWb = sWb + (long)VOC * HID;     // 32000*4096
  unsigned short* sL  = tWb + (long)VOC * HID;     // 2048*32000
  unsigned short* tL  = sL  + (long)TOK * VOC;     // 2048*32000
  float* partials = (float*)(tL + (long)TOK * VOC);

  cast_f32_bf16<<<2048, 256, 0, stream>>>(sIn, sA, (long)TOK * HID);
  cast_f32_bf16<<<2048, 256, 0, stream>>>(tIn, tA, (long)TOK * HID);
  cast_f32_bf16<<<2048, 256, 0, stream>>>(sW, sWb, (long)VOC * HID);
  cast_f32_bf16<<<2048, 256, 0, stream>>>(tW, tWb, (long)VOC * HID);

  dim3 ggrid(TOK / 128, VOC / 128);  // 16 x 250
  gemm_bt<<<ggrid, 256, 0, stream>>>(sA, sWb, sL);
  gemm_bt<<<ggrid, 256, 0, stream>>>(tA, tWb, tL);

  jsd_kernel<<<TOK, 256, 0, stream>>>(sL, tL, partials);
  final_reduce<<<1, 256, 0, stream>>>(partials, out);
}

// Round 2
// 1406.962 us; speedup vs baseline: 1.3024x; 1.3024x over previous
//
#include <hip/hip_runtime.h>
#include <stdint.h>

#define TOK 2048
#define HID 4096
#define VOC 32000
#define NKT (HID / 64)  // 64 K-tiles of BK=64

typedef __attribute__((ext_vector_type(4))) float f32x4;
typedef __attribute__((ext_vector_type(8))) short bf16x8;
typedef __attribute__((ext_vector_type(8))) unsigned short u16x8;

__device__ __forceinline__ float bf2f(unsigned short u) {
  return __uint_as_float(((unsigned int)u) << 16);
}
__device__ __forceinline__ unsigned short f2bf(float f) {
  unsigned int u = __float_as_uint(f);
  u += 0x7FFFu + ((u >> 16) & 1u);  // round-to-nearest-even
  return (unsigned short)(u >> 16);
}

// ---------------- cast f32 -> bf16 ----------------
__global__ __launch_bounds__(256) void cast_f32_bf16(const float* __restrict__ in,
                                                     unsigned short* __restrict__ out,
                                                     long n) {
  long i = ((long)blockIdx.x * 256 + threadIdx.x) * 4;
  const long stride = (long)gridDim.x * 256 * 4;
  for (; i < n; i += stride) {
    const float4 v = *(const float4*)(in + i);
    ushort4 o;
    o.x = f2bf(v.x); o.y = f2bf(v.y); o.z = f2bf(v.z); o.w = f2bf(v.w);
    *(ushort4*)(out + i) = o;
  }
}

// ---------------- async global -> LDS (16B/lane) ----------------
__device__ __forceinline__ void gload_lds16(const void* g, void* l) {
  __builtin_amdgcn_global_load_lds(
      (const __attribute__((address_space(1))) unsigned int*)(uintptr_t)g,
      (__attribute__((address_space(3))) unsigned int*)(uintptr_t)l,
      16, 0, 0);
}

// ---------------- 256x256 8-phase bf16 GEMM: C[M,N] = A[M,K] * B[N,K]^T ----------------
// 8 waves (2M x 4N), BK=64, LDS 2dbuf x 2half x [128][64] for A and B (128 KiB).
// LDS swizzle: byte ^= ((row&7)<<4) (involution; pre-swizzled global source for
// global_load_lds linear dest, same XOR on ds_read). Counted vmcnt(4) per K-tile.
__global__ __launch_bounds__(512, 2) void gemm256(const unsigned short* __restrict__ A,
                                                  const unsigned short* __restrict__ B,
                                                  unsigned short* __restrict__ C) {
  __shared__ unsigned short As[2][2][128 * 64];
  __shared__ unsigned short Bs[2][2][128 * 64];
  const int tid = threadIdx.x;
  const int w = tid >> 6;
  const int l = tid & 63;
  const int wr = w >> 2;   // 0..1 (M half)
  const int wc = w & 3;    // 0..3 (N quarter)

  // T1: XCD-aware swizzle. grid = 1000 blocks, 1000 % 8 == 0 -> simple variant OK.
  const int bid = blockIdx.x;
  const int cpx = gridDim.x >> 3;                 // 125
  const int swz = (bid & 7) * cpx + (bid >> 3);
  const int mt = swz & 7;                         // 8 M-tiles (fast within XCD chunk)
  const int nt = swz >> 3;                        // 125 N-tiles

  const size_t Abase = (size_t)mt * 256 * HID;
  const size_t Bbase = (size_t)nt * 256 * HID;

  f32x4 acc[8][4] = {};

  // staging geometry: chunk c (1 KiB) = rows c*8..c*8+7 of a [128][64] half.
  // linear LDS dest byte d = c*1024 + l*16; logical = d ^ ((row&7)<<4) with row&7 = l>>3.
  const int r8 = l >> 3;
  const int scol = ((l & 7) ^ r8) << 3;  // swizzled source column (elements)

  auto stageA = [&](int half, int v) {
    const unsigned short* src = A + Abase + (size_t)half * 128 * HID + (size_t)v * 64 + scol;
#pragma unroll
    for (int i = 0; i < 2; ++i) {
      const int c = 2 * w + i;
      gload_lds16(src + (size_t)(c * 8 + r8) * HID, &As[v & 1][half][c * 512]);
    }
  };
  auto stageB = [&](int half, int v) {
    const unsigned short* src = B + Bbase + (size_t)half * 128 * HID + (size_t)v * 64 + scol;
#pragma unroll
    for (int i = 0; i < 2; ++i) {
      const int c = 2 * w + i;
      gload_lds16(src + (size_t)(c * 8 + r8) * HID, &Bs[v & 1][half][c * 512]);
    }
  };

  // prologue: tile0 (all 4 halves) + tile1 A halves; retire tile0 (keep 4 in flight)
  stageA(0, 0); stageA(1, 0); stageB(0, 0); stageB(1, 0);
  stageA(0, 1); stageA(1, 1);
  asm volatile("s_waitcnt vmcnt(4)" ::: "memory");
  __builtin_amdgcn_s_barrier();

  const int lr = l & 15;
  const int xorv = (lr & 7) << 4;
  const int c0 = ((l >> 4) << 4) ^ xorv;  // byte col for kk=0 (16B per k-group)
  const int c1 = c0 ^ 64;                 // byte col for kk=32
  const int brow = (wc & 1) * 64;         // wave's N-row base within its B half

  for (int u = 0; u < NKT; ++u) {
    const int cur = u & 1;
    const char* Ah = (const char*)&As[cur][wr][0];
    const char* Bh = (const char*)&Bs[cur][wc >> 1][0];
    bf16x8 a0[8], a1[8], b0[4], b1[4];

    // ---- phase 1: read A-mq0 (mf0-3) + B-nq0 (nf0-1); stage B0(u+1); MFMA q(0,0) ----
#pragma unroll
    for (int mf = 0; mf < 4; ++mf) {
      const int rb = (mf * 16 + lr) << 7;
      a0[2 * mf]     = *(const bf16x8*)(Ah + rb + c0);
      a0[2 * mf + 1] = *(const bf16x8*)(Ah + rb + c1);
    }
#pragma unroll
    for (int nf = 0; nf < 2; ++nf) {
      const int rb = (brow + nf * 16 + lr) << 7;
      b0[2 * nf]     = *(const bf16x8*)(Bh + rb + c0);
      b0[2 * nf + 1] = *(const bf16x8*)(Bh + rb + c1);
    }
    if (u + 1 < NKT) stageB(0, u + 1);
    __builtin_amdgcn_s_barrier();
    asm volatile("s_waitcnt lgkmcnt(0)" ::: "memory");
    __builtin_amdgcn_sched_barrier(0);
    __builtin_amdgcn_s_setprio(1);
#pragma unroll
    for (int mf = 0; mf < 4; ++mf)
#pragma unroll
      for (int nf = 0; nf < 2; ++nf) {
        acc[mf][nf] = __builtin_amdgcn_mfma_f32_16x16x32_bf16(a0[2 * mf], b0[2 * nf], acc[mf][nf], 0, 0, 0);
        acc[mf][nf] = __builtin_amdgcn_mfma_f32_16x16x32_bf16(a0[2 * mf + 1], b0[2 * nf + 1], acc[mf][nf], 0, 0, 0);
      }
    __builtin_amdgcn_s_setprio(0);
    __builtin_amdgcn_s_barrier();

    // ---- phase 2: read A-mq1 (mf4-7); stage B1(u+1); MFMA q(1,0) ----
#pragma unroll
    for (int mf = 0; mf < 4; ++mf) {
      const int rb = ((mf + 4) * 16 + lr) << 7;
      a1[2 * mf]     = *(const bf16x8*)(Ah + rb + c0);
      a1[2 * mf + 1] = *(const bf16x8*)(Ah + rb + c1);
    }
    if (u + 1 < NKT) stageB(1, u + 1);
    __builtin_amdgcn_s_barrier();
    asm volatile("s_waitcnt lgkmcnt(0)" ::: "memory");
    __builtin_amdgcn_sched_barrier(0);
    __builtin_amdgcn_s_setprio(1);
#pragma unroll
    for (int mf = 0; mf < 4; ++mf)
#pragma unroll
      for (int nf = 0; nf < 2; ++nf) {
        acc[4 + mf][nf] = __builtin_amdgcn_mfma_f32_16x16x32_bf16(a1[2 * mf], b0[2 * nf], acc[4 + mf][nf], 0, 0, 0);
        acc[4 + mf][nf] = __builtin_amdgcn_mfma_f32_16x16x32_bf16(a1[2 * mf + 1], b0[2 * nf + 1], acc[4 + mf][nf], 0, 0, 0);
      }
    __builtin_amdgcn_s_setprio(0);
    __builtin_amdgcn_s_barrier();

    // ---- phase 3: read B-nq1 (nf2-3); stage A0(u+2) [A reads of tile u ended ph2]; MFMA q(1,1) ----
#pragma unroll
    for (int nf = 0; nf < 2; ++nf) {
      const int rb = (brow + (nf + 2) * 16 + lr) << 7;
      b1[2 * nf]     = *(const bf16x8*)(Bh + rb + c0);
      b1[2 * nf + 1] = *(const bf16x8*)(Bh + rb + c1);
    }
    if (u + 2 < NKT) stageA(0, u + 2);
    __builtin_amdgcn_s_barrier();
    asm volatile("s_waitcnt lgkmcnt(0)" ::: "memory");
    __builtin_amdgcn_sched_barrier(0);
    __builtin_amdgcn_s_setprio(1);
#pragma unroll
    for (int mf = 0; mf < 4; ++mf)
#pragma unroll
      for (int nf = 0; nf < 2; ++nf) {
        acc[4 + mf][2 + nf] = __builtin_amdgcn_mfma_f32_16x16x32_bf16(a1[2 * mf], b1[2 * nf], acc[4 + mf][2 + nf], 0, 0, 0);
        acc[4 + mf][2 + nf] = __builtin_amdgcn_mfma_f32_16x16x32_bf16(a1[2 * mf + 1], b1[2 * nf + 1], acc[4 + mf][2 + nf], 0, 0, 0);
      }
    __builtin_amdgcn_s_setprio(0);
    __builtin_amdgcn_s_barrier();

    // ---- phase 4: stage A1(u+2); MFMA q(0,1) (a0 held since ph1); counted vmcnt ----
    if (u + 2 < NKT) stageA(1, u + 2);
    __builtin_amdgcn_s_barrier();
    __builtin_amdgcn_s_setprio(1);
#pragma unroll
    for (int mf = 0; mf < 4; ++mf)
#pragma unroll
      for (int nf = 0; nf < 2; ++nf) {
        acc[mf][2 + nf] = __builtin_amdgcn_mfma_f32_16x16x32_bf16(a0[2 * mf], b1[2 * nf], acc[mf][2 + nf], 0, 0, 0);
        acc[mf][2 + nf] = __builtin_amdgcn_mfma_f32_16x16x32_bf16(a0[2 * mf + 1], b1[2 * nf + 1], acc[mf][2 + nf], 0, 0, 0);
      }
    __builtin_amdgcn_s_setprio(0);
    if (u + 2 < NKT) {
      asm volatile("s_waitcnt vmcnt(4)" ::: "memory");  // keep A(u+2) halves in flight
    } else {
      asm volatile("s_waitcnt vmcnt(0)" ::: "memory");  // drain at tail
    }
    __builtin_amdgcn_s_barrier();
  }

  // epilogue: D col = lane&15 (N), row = (lane>>4)*4 + reg (M)
  const int lg = (l >> 4) * 4;
#pragma unroll
  for (int mf = 0; mf < 8; ++mf)
#pragma unroll
    for (int nf = 0; nf < 4; ++nf)
#pragma unroll
      for (int r = 0; r < 4; ++r) {
        const int row = mt * 256 + wr * 128 + mf * 16 + lg + r;
        const int col = nt * 256 + wc * 64 + nf * 16 + lr;
        C[(size_t)row * VOC + col] = f2bf(acc[mf][nf][r]);
      }
}

// ---------------- per-token JSD ----------------
__device__ __forceinline__ void merge_ms(float& m, float& s, float om, float os) {
  float nm = fmaxf(m, om);
  s = s * __expf(m - nm) + os * __expf(om - nm);
  m = nm;
}

__global__ __launch_bounds__(256) void jsd_kernel(const unsigned short* __restrict__ SL,
                                                  const unsigned short* __restrict__ TL,
                                                  float* __restrict__ partials) {
  const int t = blockIdx.x;
  const int tid = threadIdx.x;
  const unsigned short* srow = SL + (size_t)t * VOC;
  const unsigned short* trow = TL + (size_t)t * VOC;

  float ms = -INFINITY, ss = 0.f, mt_ = -INFINITY, st = 0.f;
  for (int c = tid; c < VOC / 8; c += 256) {
    u16x8 vs = *(const u16x8*)(srow + c * 8);
    u16x8 vt = *(const u16x8*)(trow + c * 8);
    float zs[8], zt[8];
    float m8s = -INFINITY, m8t = -INFINITY;
#pragma unroll
    for (int j = 0; j < 8; ++j) {
      zs[j] = bf2f(vs[j]); zt[j] = bf2f(vt[j]);
      m8s = fmaxf(m8s, zs[j]); m8t = fmaxf(m8t, zt[j]);
    }
    float nms = fmaxf(ms, m8s);
    float es = 0.f;
#pragma unroll
    for (int j = 0; j < 8; ++j) es += __expf(zs[j] - nms);
    ss = ss * __expf(ms - nms) + es; ms = nms;
    float nmt = fmaxf(mt_, m8t);
    float et = 0.f;
#pragma unroll
    for (int j = 0; j < 8; ++j) et += __expf(zt[j] - nmt);
    st = st * __expf(mt_ - nmt) + et; mt_ = nmt;
  }
#pragma unroll
  for (int off = 32; off > 0; off >>= 1) {
    float om = __shfl_xor(ms, off), os = __shfl_xor(ss, off);
    merge_ms(ms, ss, om, os);
    float omt = __shfl_xor(mt_, off), ost = __shfl_xor(st, off);
    merge_ms(mt_, st, omt, ost);
  }
  __shared__ float red[4][4];
  const int w = tid >> 6;
  if ((tid & 63) == 0) { red[w][0] = ms; red[w][1] = ss; red[w][2] = mt_; red[w][3] = st; }
  __syncthreads();
  float Ms = red[0][0], Ss = red[0][1], Mt = red[0][2], St = red[0][3];
#pragma unroll
  for (int i = 1; i < 4; ++i) {
    merge_ms(Ms, Ss, red[i][0], red[i][1]);
    merge_ms(Mt, St, red[i][2], red[i][3]);
  }
  const float logZs = Ms + __logf(Ss);
  const float logZt = Mt + __logf(St);

  float acc = 0.f;
  for (int c = tid; c < VOC / 8; c += 256) {
    u16x8 vs = *(const u16x8*)(srow + c * 8);
    u16x8 vt = *(const u16x8*)(trow + c * 8);
#pragma unroll
    for (int j = 0; j < 8; ++j) {
      float lq = bf2f(vs[j]) - logZs;
      float lp = bf2f(vt[j]) - logZt;
      float mx = fmaxf(lp, lq), mn = fminf(lp, lq);
      float lm = mx + log1pf(__expf(mn - mx)) - 0.69314718f;
      acc += __expf(lp) * (lp - lm) + __expf(lq) * (lq - lm);
    }
  }
  acc *= 0.5f;
#pragma unroll
  for (int off = 32; off > 0; off >>= 1) acc += __shfl_xor(acc, off);
  __shared__ float red2[4];
  if ((tid & 63) == 0) red2[w] = acc;
  __syncthreads();
  if (tid == 0) partials[t] = red2[0] + red2[1] + red2[2] + red2[3];
}

__global__ __launch_bounds__(256) void final_reduce(const float* __restrict__ partials,
                                                    float* __restrict__ out) {
  float a = 0.f;
  for (int i = threadIdx.x; i < TOK; i += 256) a += partials[i];
#pragma unroll
  for (int off = 32; off > 0; off >>= 1) a += __shfl_xor(a, off);
  __shared__ float red[4];
  const int w = threadIdx.x >> 6;
  if ((threadIdx.x & 63) == 0) red[w] = a;
  __syncthreads();
  if (threadIdx.x == 0) out[0] = (red[0] + red[1] + red[2] + red[3]) * (1.0f / TOK);
}

// ---------------- launch ----------------
extern "C" void kernel_launch(void* const* d_in, const int* in_sizes, int n_in,
                              void* d_out, int out_size, void* d_ws, size_t ws_size,
                              hipStream_t stream) {
  const float* sIn = (const float*)d_in[0];
  const float* tIn = (const float*)d_in[1];
  const float* sW  = (const float*)d_in[2];
  const float* tW  = (const float*)d_in[3];
  float* out = (float*)d_out;

  unsigned short* ws = (unsigned short*)d_ws;
  unsigned short* sA  = ws;
  unsigned short* tA  = sA  + (long)TOK * HID;
  unsigned short* sWb = tA  + (long)TOK * HID;
  unsigned short* tWb = sWb + (long)VOC * HID;
  unsigned short* sL  = tWb + (long)VOC * HID;
  unsigned short* tL  = sL  + (long)TOK * VOC;
  float* partials = (float*)(tL + (long)TOK * VOC);

  cast_f32_bf16<<<2048, 256, 0, stream>>>(sIn, sA, (long)TOK * HID);
  cast_f32_bf16<<<2048, 256, 0, stream>>>(tIn, tA, (long)TOK * HID);
  cast_f32_bf16<<<2048, 256, 0, stream>>>(sW, sWb, (long)VOC * HID);
  cast_f32_bf16<<<2048, 256, 0, stream>>>(tW, tWb, (long)VOC * HID);

  const int nblk = (TOK / 256) * (VOC / 256);  // 8 * 125 = 1000
  gemm256<<<nblk, 512, 0, stream>>>(sA, sWb, sL);
  gemm256<<<nblk, 512, 0, stream>>>(tA, tWb, tL);

  jsd_kernel<<<TOK, 256, 0, stream>>>(sL, tL, partials);
  final_reduce<<<1, 256, 0, stream>>>(partials, out);
}

// Round 3
// 1373.807 us; speedup vs baseline: 1.3339x; 1.0241x over previous
//
#include <hip/hip_runtime.h>
#include <stdint.h>

#define TOK 2048
#define HID 4096
#define VOC 32000
#define NKT (HID / 64)  // 64 K-tiles of BK=64

typedef __attribute__((ext_vector_type(4))) float f32x4;
typedef __attribute__((ext_vector_type(8))) short bf16x8;
typedef __attribute__((ext_vector_type(8))) unsigned short u16x8;

__device__ __forceinline__ float bf2f(unsigned short u) {
  return __uint_as_float(((unsigned int)u) << 16);
}
__device__ __forceinline__ unsigned short f2bf(float f) {
  unsigned int u = __float_as_uint(f);
  u += 0x7FFFu + ((u >> 16) & 1u);  // round-to-nearest-even
  return (unsigned short)(u >> 16);
}

// ---------------- cast f32 -> bf16 ----------------
__global__ __launch_bounds__(256) void cast_f32_bf16(const float* __restrict__ in,
                                                     unsigned short* __restrict__ out,
                                                     long n) {
  long i = ((long)blockIdx.x * 256 + threadIdx.x) * 4;
  const long stride = (long)gridDim.x * 256 * 4;
  for (; i < n; i += stride) {
    const float4 v = *(const float4*)(in + i);
    ushort4 o;
    o.x = f2bf(v.x); o.y = f2bf(v.y); o.z = f2bf(v.z); o.w = f2bf(v.w);
    *(ushort4*)(out + i) = o;
  }
}

// ---------------- async global -> LDS (16B/lane) ----------------
__device__ __forceinline__ void gload_lds16(const void* g, void* l) {
  __builtin_amdgcn_global_load_lds(
      (const __attribute__((address_space(1))) unsigned int*)(uintptr_t)g,
      (__attribute__((address_space(3))) unsigned int*)(uintptr_t)l,
      16, 0, 0);
}

// ---------------- 256x256 bf16 GEMM, 2-barrier-per-K-tile schedule ----------------
// C[M,N] = A[M,K] * B[N,K]^T. 8 waves (2M x 4N), BK=64,
// LDS 2dbuf x 2half x [128][64] for A and B (128 KiB).
// Swizzle: byte ^= ((row&7)<<4) (pre-swizzled global source, same XOR on ds_read).
// Hazards covered: (1) A-reads drain (lgkmcnt0+barrier) before stageA(u+2) issue
// (writes current buffer); (2) counted vmcnt(4) retires A(u+1)+B(u+1) at tile end,
// keeps A(u+2) in flight. Everything else: compiler's fine-grained auto-lgkmcnt.
__global__ __launch_bounds__(512, 2) void gemm256(const unsigned short* __restrict__ A,
                                                  const unsigned short* __restrict__ B,
                                                  unsigned short* __restrict__ C) {
  __shared__ unsigned short As[2][2][128 * 64];
  __shared__ unsigned short Bs[2][2][128 * 64];
  const int tid = threadIdx.x;
  const int w = tid >> 6;
  const int l = tid & 63;
  const int wr = w >> 2;   // 0..1 (M half)
  const int wc = w & 3;    // 0..3 (N quarter)

  // T1: XCD-aware swizzle. grid = 1000 blocks, 1000 % 8 == 0.
  const int bid = blockIdx.x;
  const int cpx = gridDim.x >> 3;                 // 125
  const int swz = (bid & 7) * cpx + (bid >> 3);
  const int mt = swz & 7;                         // 8 M-tiles (fast within XCD chunk)
  const int nt = swz >> 3;                        // 125 N-tiles

  const size_t Abase = (size_t)mt * 256 * HID;
  const size_t Bbase = (size_t)nt * 256 * HID;

  f32x4 acc[8][4] = {};

  // staging: chunk c (1 KiB) = rows c*8..c*8+7 of a [128][64] half.
  // linear LDS dest byte d = c*1024 + l*16; logical = d ^ ((row&7)<<4), row&7 = l>>3.
  const int r8 = l >> 3;
  const int scol = ((l & 7) ^ r8) << 3;  // swizzled source column (elements)

  auto stageA = [&](int half, int v) {
    const unsigned short* src = A + Abase + (size_t)half * 128 * HID + (size_t)v * 64 + scol;
#pragma unroll
    for (int i = 0; i < 2; ++i) {
      const int c = 2 * w + i;
      gload_lds16(src + (size_t)(c * 8 + r8) * HID, &As[v & 1][half][c * 512]);
    }
  };
  auto stageB = [&](int half, int v) {
    const unsigned short* src = B + Bbase + (size_t)half * 128 * HID + (size_t)v * 64 + scol;
#pragma unroll
    for (int i = 0; i < 2; ++i) {
      const int c = 2 * w + i;
      gload_lds16(src + (size_t)(c * 8 + r8) * HID, &Bs[v & 1][half][c * 512]);
    }
  };

  // prologue: tile0 all halves + tile1 A halves; retire tile0's 8 (keep A(1) in flight)
  stageA(0, 0); stageA(1, 0); stageB(0, 0); stageB(1, 0);
  stageA(0, 1); stageA(1, 1);
  asm volatile("s_waitcnt vmcnt(4)" ::: "memory");
  __builtin_amdgcn_s_barrier();

  const int lr = l & 15;
  const int c0 = ((l >> 4) << 4) ^ ((lr & 7) << 4);  // byte col for kk=0
  const int c1 = c0 ^ 64;                            // byte col for kk=32
  const int brow = (wc & 1) * 64;                    // wave's N-row base in its B half

#pragma unroll 2
  for (int u = 0; u < NKT; ++u) {
    const int cur = u & 1;
    const char* Ah = (const char*)&As[cur][wr][0];
    const char* Bh = (const char*)&Bs[cur][wc >> 1][0];
    bf16x8 a0[8], a1[8], b0[4], b1[4];

    // ---- issue all 24 ds_reads (compiler schedules + counted auto-lgkmcnt) ----
#pragma unroll
    for (int mf = 0; mf < 4; ++mf) {
      const int rb = (mf * 16 + lr) << 7;
      a0[2 * mf]     = *(const bf16x8*)(Ah + rb + c0);
      a0[2 * mf + 1] = *(const bf16x8*)(Ah + rb + c1);
    }
#pragma unroll
    for (int nf = 0; nf < 2; ++nf) {
      const int rb = (brow + nf * 16 + lr) << 7;
      b0[2 * nf]     = *(const bf16x8*)(Bh + rb + c0);
      b0[2 * nf + 1] = *(const bf16x8*)(Bh + rb + c1);
    }
#pragma unroll
    for (int mf = 0; mf < 4; ++mf) {
      const int rb = ((mf + 4) * 16 + lr) << 7;
      a1[2 * mf]     = *(const bf16x8*)(Ah + rb + c0);
      a1[2 * mf + 1] = *(const bf16x8*)(Ah + rb + c1);
    }
#pragma unroll
    for (int nf = 0; nf < 2; ++nf) {
      const int rb = (brow + (nf + 2) * 16 + lr) << 7;
      b1[2 * nf]     = *(const bf16x8*)(Bh + rb + c0);
      b1[2 * nf + 1] = *(const bf16x8*)(Bh + rb + c1);
    }

    // stage B(u+1) into buf cur^1 (no conflict with current reads)
    if (u + 1 < NKT) { stageB(0, u + 1); stageB(1, u + 1); }

    __builtin_amdgcn_s_setprio(1);
    // q(0,0), q(1,0), q(1,1): 48 MFMA, reads interleave via auto-waits
#pragma unroll
    for (int mf = 0; mf < 4; ++mf)
#pragma unroll
      for (int nf = 0; nf < 2; ++nf) {
        acc[mf][nf] = __builtin_amdgcn_mfma_f32_16x16x32_bf16(a0[2 * mf], b0[2 * nf], acc[mf][nf], 0, 0, 0);
        acc[mf][nf] = __builtin_amdgcn_mfma_f32_16x16x32_bf16(a0[2 * mf + 1], b0[2 * nf + 1], acc[mf][nf], 0, 0, 0);
      }
#pragma unroll
    for (int mf = 0; mf < 4; ++mf)
#pragma unroll
      for (int nf = 0; nf < 2; ++nf) {
        acc[4 + mf][nf] = __builtin_amdgcn_mfma_f32_16x16x32_bf16(a1[2 * mf], b0[2 * nf], acc[4 + mf][nf], 0, 0, 0);
        acc[4 + mf][nf] = __builtin_amdgcn_mfma_f32_16x16x32_bf16(a1[2 * mf + 1], b0[2 * nf + 1], acc[4 + mf][nf], 0, 0, 0);
      }
#pragma unroll
    for (int mf = 0; mf < 4; ++mf)
#pragma unroll
      for (int nf = 0; nf < 2; ++nf) {
        acc[4 + mf][2 + nf] = __builtin_amdgcn_mfma_f32_16x16x32_bf16(a1[2 * mf], b1[2 * nf], acc[4 + mf][2 + nf], 0, 0, 0);
        acc[4 + mf][2 + nf] = __builtin_amdgcn_mfma_f32_16x16x32_bf16(a1[2 * mf + 1], b1[2 * nf + 1], acc[4 + mf][2 + nf], 0, 0, 0);
      }
    __builtin_amdgcn_s_setprio(0);

    // all reads of this tile's buffers must have landed before stageA(u+2)
    // (writes As[cur]) can be issued by any wave
    asm volatile("s_waitcnt lgkmcnt(0)" ::: "memory");
    __builtin_amdgcn_s_barrier();

    if (u + 2 < NKT) { stageA(0, u + 2); stageA(1, u + 2); }

    __builtin_amdgcn_s_setprio(1);
    // q(0,1): register-only (a0, b1 held) — covers stage-issue + vmcnt shadow
#pragma unroll
    for (int mf = 0; mf < 4; ++mf)
#pragma unroll
      for (int nf = 0; nf < 2; ++nf) {
        acc[mf][2 + nf] = __builtin_amdgcn_mfma_f32_16x16x32_bf16(a0[2 * mf], b1[2 * nf], acc[mf][2 + nf], 0, 0, 0);
        acc[mf][2 + nf] = __builtin_amdgcn_mfma_f32_16x16x32_bf16(a0[2 * mf + 1], b1[2 * nf + 1], acc[mf][2 + nf], 0, 0, 0);
      }
    __builtin_amdgcn_s_setprio(0);

    if (u + 2 < NKT) {
      asm volatile("s_waitcnt vmcnt(4)" ::: "memory");  // retire A(u+1)+B(u+1), keep A(u+2) flying
      __builtin_amdgcn_s_barrier();
    } else if (u + 1 < NKT) {
      asm volatile("s_waitcnt vmcnt(0)" ::: "memory");  // tail: last tile needs A,B(NKT-1)
      __builtin_amdgcn_s_barrier();
    }
  }

  // epilogue: D col = lane&15 (N), row = (lane>>4)*4 + reg (M)
  const int lg = (l >> 4) * 4;
#pragma unroll
  for (int mf = 0; mf < 8; ++mf)
#pragma unroll
    for (int nf = 0; nf < 4; ++nf)
#pragma unroll
      for (int r = 0; r < 4; ++r) {
        const int row = mt * 256 + wr * 128 + mf * 16 + lg + r;
        const int col = nt * 256 + wc * 64 + nf * 16 + lr;
        C[(size_t)row * VOC + col] = f2bf(acc[mf][nf][r]);
      }
}

// ---------------- per-token JSD ----------------
__device__ __forceinline__ void merge_ms(float& m, float& s, float om, float os) {
  float nm = fmaxf(m, om);
  s = s * __expf(m - nm) + os * __expf(om - nm);
  m = nm;
}

__global__ __launch_bounds__(256) void jsd_kernel(const unsigned short* __restrict__ SL,
                                                  const unsigned short* __restrict__ TL,
                                                  float* __restrict__ partials) {
  const int t = blockIdx.x;
  const int tid = threadIdx.x;
  const unsigned short* srow = SL + (size_t)t * VOC;
  const unsigned short* trow = TL + (size_t)t * VOC;

  float ms = -INFINITY, ss = 0.f, mt_ = -INFINITY, st = 0.f;
  for (int c = tid; c < VOC / 8; c += 256) {
    u16x8 vs = *(const u16x8*)(srow + c * 8);
    u16x8 vt = *(const u16x8*)(trow + c * 8);
    float zs[8], zt[8];
    float m8s = -INFINITY, m8t = -INFINITY;
#pragma unroll
    for (int j = 0; j < 8; ++j) {
      zs[j] = bf2f(vs[j]); zt[j] = bf2f(vt[j]);
      m8s = fmaxf(m8s, zs[j]); m8t = fmaxf(m8t, zt[j]);
    }
    float nms = fmaxf(ms, m8s);
    float es = 0.f;
#pragma unroll
    for (int j = 0; j < 8; ++j) es += __expf(zs[j] - nms);
    ss = ss * __expf(ms - nms) + es; ms = nms;
    float nmt = fmaxf(mt_, m8t);
    float et = 0.f;
#pragma unroll
    for (int j = 0; j < 8; ++j) et += __expf(zt[j] - nmt);
    st = st * __expf(mt_ - nmt) + et; mt_ = nmt;
  }
#pragma unroll
  for (int off = 32; off > 0; off >>= 1) {
    float om = __shfl_xor(ms, off), os = __shfl_xor(ss, off);
    merge_ms(ms, ss, om, os);
    float omt = __shfl_xor(mt_, off), ost = __shfl_xor(st, off);
    merge_ms(mt_, st, omt, ost);
  }
  __shared__ float red[4][4];
  const int w = tid >> 6;
  if ((tid & 63) == 0) { red[w][0] = ms; red[w][1] = ss; red[w][2] = mt_; red[w][3] = st; }
  __syncthreads();
  float Ms = red[0][0], Ss = red[0][1], Mt = red[0][2], St = red[0][3];
#pragma unroll
  for (int i = 1; i < 4; ++i) {
    merge_ms(Ms, Ss, red[i][0], red[i][1]);
    merge_ms(Mt, St, red[i][2], red[i][3]);
  }
  const float logZs = Ms + __logf(Ss);
  const float logZt = Mt + __logf(St);

  float acc = 0.f;
  for (int c = tid; c < VOC / 8; c += 256) {
    u16x8 vs = *(const u16x8*)(srow + c * 8);
    u16x8 vt = *(const u16x8*)(trow + c * 8);
#pragma unroll
    for (int j = 0; j < 8; ++j) {
      float lq = bf2f(vs[j]) - logZs;
      float lp = bf2f(vt[j]) - logZt;
      float mx = fmaxf(lp, lq), mn = fminf(lp, lq);
      float lm = mx + log1pf(__expf(mn - mx)) - 0.69314718f;
      acc += __expf(lp) * (lp - lm) + __expf(lq) * (lq - lm);
    }
  }
  acc *= 0.5f;
#pragma unroll
  for (int off = 32; off > 0; off >>= 1) acc += __shfl_xor(acc, off);
  __shared__ float red2[4];
  if ((tid & 63) == 0) red2[w] = acc;
  __syncthreads();
  if (tid == 0) partials[t] = red2[0] + red2[1] + red2[2] + red2[3];
}

__global__ __launch_bounds__(256) void final_reduce(const float* __restrict__ partials,
                                                    float* __restrict__ out) {
  float a = 0.f;
  for (int i = threadIdx.x; i < TOK; i += 256) a += partials[i];
#pragma unroll
  for (int off = 32; off > 0; off >>= 1) a += __shfl_xor(a, off);
  __shared__ float red[4];
  const int w = threadIdx.x >> 6;
  if ((threadIdx.x & 63) == 0) red[w] = a;
  __syncthreads();
  if (threadIdx.x == 0) out[0] = (red[0] + red[1] + red[2] + red[3]) * (1.0f / TOK);
}

// ---------------- launch ----------------
extern "C" void kernel_launch(void* const* d_in, const int* in_sizes, int n_in,
                              void* d_out, int out_size, void* d_ws, size_t ws_size,
                              hipStream_t stream) {
  const float* sIn = (const float*)d_in[0];
  const float* tIn = (const float*)d_in[1];
  const float* sW  = (const float*)d_in[2];
  const float* tW  = (const float*)d_in[3];
  float* out = (float*)d_out;

  unsigned short* ws = (unsigned short*)d_ws;
  unsigned short* sA  = ws;
  unsigned short* tA  = sA  + (long)TOK * HID;
  unsigned short* sWb = tA  + (long)TOK * HID;
  unsigned short* tWb = sWb + (long)VOC * HID;
  unsigned short* sL  = tWb + (long)VOC * HID;
  unsigned short* tL  = sL  + (long)TOK * VOC;
  float* partials = (float*)(tL + (long)TOK * VOC);

  cast_f32_bf16<<<2048, 256, 0, stream>>>(sIn, sA, (long)TOK * HID);
  cast_f32_bf16<<<2048, 256, 0, stream>>>(tIn, tA, (long)TOK * HID);
  cast_f32_bf16<<<2048, 256, 0, stream>>>(sW, sWb, (long)VOC * HID);
  cast_f32_bf16<<<2048, 256, 0, stream>>>(tW, tWb, (long)VOC * HID);

  const int nblk = (TOK / 256) * (VOC / 256);  // 8 * 125 = 1000
  gemm256<<<nblk, 512, 0, stream>>>(sA, sWb, sL);
  gemm256<<<nblk, 512, 0, stream>>>(tA, tWb, tL);

  jsd_kernel<<<TOK, 256, 0, stream>>>(sL, tL, partials);
  final_reduce<<<1, 256, 0, stream>>>(partials, out);
}